// Round 15
// baseline (250.037 us; speedup 1.0000x reference)
//
#include <hip/hip_runtime.h>
#include <hip/hip_fp16.h>

#define N_NODES 50000
#define N_EDGES 400000
#define CSR_E (2 * N_EDGES + N_NODES) /* 850000, fits 20 bits */
#define NCH 10        /* source chunks */
#define CHW 5000      /* chunk width: 5000 nodes * 256B = 1.28MB window */
#define NE2 (N_NODES * NCH) /* buckets: (node, chunk), node-major contiguous */
#define EB8 196       /* cdiv(N_EDGES,2048) edge blocks, 8 edges/thread */
#define PB 288        /* prep blocks: (2*32768+8192)/256 */
#define CB 512        /* conv blocks (grid-stride; no-op when bf16 input) */
#define RB_SCAN 489   /* cdiv(NE2,1024) scan blocks */
#define RB_DEGC 49    /* cdiv(N_NODES,1024) deg-extract blocks (ride the scan dispatch) */

typedef unsigned short ushort_t;
typedef unsigned int uint_t;
typedef unsigned long long ull_t;
typedef __attribute__((ext_vector_type(8))) short bf16x8;
typedef __attribute__((ext_vector_type(4))) float f32x4;

__device__ __forceinline__ float bf2f(ushort_t u) {
    return __uint_as_float(((uint_t)u) << 16);
}
__device__ __forceinline__ ushort_t f2bf(float f) {
    uint_t b = __float_as_uint(f);
    b += 0x7FFFu + ((b >> 16) & 1u); // RNE
    return (ushort_t)(b >> 16);
}
// fp16 pair packing for CSR entry weights (low = S-channel, high = D-channel)
__device__ __forceinline__ uint_t packw(float a, float b) {
    return ((uint_t)__half_as_ushort(__float2half(b)) << 16) |
           (uint_t)__half_as_ushort(__float2half(a));
}
__device__ __forceinline__ float unpl(uint_t w) {
    return __half2float(__ushort_as_half((ushort_t)(w & 0xffffu)));
}
__device__ __forceinline__ float unph(uint_t w) {
    return __half2float(__ushort_as_half((ushort_t)(w >> 16)));
}
// 2^16 fixed-point for degree sums packed into the bucket atomic
__device__ __forceinline__ uint_t fixw(float x) {
    return (uint_t)(x * 65536.0f + 0.5f); // <= 65536, fits 26-bit field
}

// ---------------- static device scratch (module BSS; d_ws untouched) ----------------
// Self-maintaining invariants across launches (graph replay): g_cnt64 zeroed by
// fill_all after scan+deg consumed it; g_scanst zeroed by fill_all. BSS starts 0.
// NOTE (r13 post-mortem): intra-kernel spin barriers are triple-confirmed dead
// on MI355X (r3 coop, r10 multi-phase, r13 single-barrier all regressed 2-5x).
// The ~4us dispatch boundary is strictly cheaper than any device-scope spin.

__device__ int g_est;  // edge-index word stride: 1 = int32, 2 = int64
__device__ int g_is16; // 1 = float tensors bf16-packed, 0 = fp32
__device__ __align__(8) float2 g_dis2[N_NODES]; // (dis_s, dis_r)
// bucket word: count(12) | S-sum fix16(26)<<12 | D-sum fix16(26)<<38
// S = sum of in_w (deg_s via pairing identity), D = sum of out_w (deg_r)
__device__ ull_t g_cnt64[NE2];
__device__ int g_offs2[NE2 + 1];
__device__ uint_t g_scanst[512];   // lookback scan status: bits[21:20]=flag, [19:0]=value
__device__ __align__(16) uint4 g_estage[N_EDGES]; // {s, r, c2 bits, ranks(lo=fwd,hi=rev)}
__device__ __align__(16) uint2 g_csr8[CSR_E]; // {src, half2 w}: FINAL src-folded weights
__device__ __align__(16) ushort_t g_h1[(size_t)N_NODES * 128];  // bf16
__device__ __align__(16) ushort_t g_xcvt[(size_t)N_NODES * 128]; // bf16 (fp32-input fallback)
__device__ __align__(16) ushort_t g_bp1[8 * 128 * 32]; // B packed [kb][n][kk] bf16
__device__ __align__(16) ushort_t g_bp2[8 * 128 * 32];
__device__ __align__(16) ushort_t g_bp3[4 * 64 * 32];
__device__ float g_bc1[128];
__device__ float g_bc2[128];
__device__ float g_bro[64];

// ---------------- edge pass + weight prep + conv, role-split by block (r14 verbatim) ----------------

__global__ __launch_bounds__(256) void edge_prep(
    const uint_t* __restrict__ xw,
    const int* __restrict__ eidx, const ushort_t* __restrict__ th16, const float* __restrict__ th32,
    const ushort_t* W1s16, const float* W1s32, const ushort_t* W1d16, const float* W1d32,
    const ushort_t* b1s16, const float* b1s32, const ushort_t* b1d16, const float* b1d32,
    const ushort_t* W2s16, const float* W2s32, const ushort_t* W2d16, const float* W2d32,
    const ushort_t* b2s16, const float* b2s32, const ushort_t* b2d16, const float* b2d32,
    const ushort_t* Wro16, const float* Wro32, const ushort_t* bro16, const float* bro32) {
    __shared__ int s_flags;
    if (threadIdx.x < 64) {
        uint_t w = xw[threadIdx.x];
        int elo = (w >> 7) & 0xFF;
        unsigned long long mb = __ballot(elo >= 100 && elo <= 150);
        unsigned long long me = __ballot(eidx[2 * threadIdx.x + 1] != 0);
        if (threadIdx.x == 0) {
            int is16v = (__popcll(mb) >= 48) ? 1 : 0;
            int estv = me ? 1 : 2;
            s_flags = is16v | (estv << 1);
        }
    }
    __syncthreads();
    int is16 = s_flags & 1;
    int est = s_flags >> 1;
    int gb = blockIdx.x;
    if (gb == 0 && threadIdx.x == 0) { // publish for later kernels
        g_is16 = is16;
        g_est = est;
    }
    if (gb < EB8) {
        int base = gb * 2048 + threadIdx.x;
        int sv[8], rv[8];
        float th[8];
#pragma unroll
        for (int u = 0; u < 8; u++) {
            int e = base + u * 256;
            if (e < N_EDGES) {
                sv[u] = eidx[(size_t)e * est];
                rv[u] = eidx[((size_t)N_EDGES + e) * est];
                th[u] = is16 ? bf2f(th16[e]) : th32[e];
            } else { sv[u] = 0; rv[u] = 0; th[u] = 0.f; }
        }
        float c2v[8];
#pragma unroll
        for (int u = 0; u < 8; u++) {
            float sn, cs_;
            sincosf(th[u], &sn, &cs_);
            c2v[u] = cs_ * cs_;
        }
        uint_t rf[8], rr_[8];
#pragma unroll
        for (int u = 0; u < 8; u++) {
            int e = base + u * 256;
            if (e < N_EDGES) {
                uint_t fc2 = fixw(c2v[u]);
                uint_t fs2 = fixw(1.0f - c2v[u]);
                // fwd entry lands in r's bucket: in_w=s2 (S), out_w=c2 (D)
                ull_t af = 1ull | ((ull_t)fs2 << 12) | ((ull_t)fc2 << 38);
                // rev entry lands in s's bucket: in_w=c2 (S), out_w=s2 (D)
                ull_t ar = 1ull | ((ull_t)fc2 << 12) | ((ull_t)fs2 << 38);
                ull_t retf = atomicAdd(&g_cnt64[rv[u] * NCH + sv[u] / CHW], af);
                ull_t retr = atomicAdd(&g_cnt64[sv[u] * NCH + rv[u] / CHW], ar);
                rf[u] = (uint_t)(retf & 0xFFFull);
                rr_[u] = (uint_t)(retr & 0xFFFull);
            } else { rf[u] = 0; rr_[u] = 0; }
        }
#pragma unroll
        for (int u = 0; u < 8; u++) {
            int e = base + u * 256;
            if (e < N_EDGES)
                g_estage[e] = make_uint4((uint_t)sv[u], (uint_t)rv[u], __float_as_uint(c2v[u]),
                                         rf[u] | (rr_[u] << 16));
        }
        return;
    }
    if (gb < EB8 + PB) {
        int t = (gb - EB8) * 256 + threadIdx.x; // 0..73727
        if (t < 2 * 32768) { // hidden layers
            int layer = t >> 15;
            int i = t & 32767;
            const ushort_t* Ws16 = layer ? W2s16 : W1s16;
            const float* Ws32 = layer ? W2s32 : W1s32;
            const ushort_t* Wd16 = layer ? W2d16 : W1d16;
            const float* Wd32 = layer ? W2d32 : W1d32;
            ushort_t* Bp = layer ? g_bp2 : g_bp1;
            int k = i >> 7, n = i & 127;
            ushort_t v;
            if (k < 128) {
                int idx = k * 128 + n;
                v = is16 ? Ws16[idx] : f2bf(Ws32[idx]);
            } else {
                int idx = (k - 128) * 128 + n;
                v = is16 ? Wd16[idx] : f2bf(Wd32[idx]);
            }
            int kb = k >> 5, kk = k & 31;
            Bp[((kb * 128 + n) << 5) + kk] = v;
            if (i < 128) {
                const ushort_t* bs16 = layer ? b2s16 : b1s16;
                const float* bs32 = layer ? b2s32 : b1s32;
                const ushort_t* bd16 = layer ? b2d16 : b1d16;
                const float* bd32 = layer ? b2d32 : b1d32;
                float a = is16 ? bf2f(bs16[i]) : bs32[i];
                float b = is16 ? bf2f(bd16[i]) : bd32[i];
                (layer ? g_bc2 : g_bc1)[i] = 0.5f * (a + b);
            }
        } else { // readout (t < 73728)
            int i = t - 2 * 32768;
            int k = i >> 6, n = i & 63;
            ushort_t v = is16 ? Wro16[i] : f2bf(Wro32[i]);
            int kb = k >> 5, kk = k & 31;
            g_bp3[((kb * 64 + n) << 5) + kk] = v;
            if (i < 64) g_bro[i] = is16 ? bf2f(bro16[i]) : bro32[i];
        }
        return;
    }
    // conv role: fp32 -> bf16 (no-op when input already bf16)
    if (is16) return;
    const float* x32 = (const float*)xw;
    const int total = N_NODES * 128 / 8;
    for (int i = (gb - EB8 - PB) * 256 + threadIdx.x; i < total; i += CB * 256) {
        const float4* p = (const float4*)(x32 + (size_t)i * 8);
        float4 a = p[0], b = p[1];
        ushort4 o0, o1;
        o0.x = f2bf(a.x); o0.y = f2bf(a.y); o0.z = f2bf(a.z); o0.w = f2bf(a.w);
        o1.x = f2bf(b.x); o1.y = f2bf(b.y); o1.z = f2bf(b.z); o1.w = f2bf(b.w);
        *(ushort4*)(g_xcvt + (size_t)i * 8) = o0;
        *(ushort4*)(g_xcvt + (size_t)i * 8 + 4) = o1;
    }
}

// ---------------- scan + degree extraction in ONE dispatch (r14 verbatim) ----------------

__global__ __launch_bounds__(1024) void scan_deg() {
    int gb = blockIdx.x;
    int t = threadIdx.x;
    if (gb >= RB_SCAN) {
        // ---- deg role ----
        int n = (gb - RB_SCAN) * 1024 + t;
        if (n < N_NODES) {
            ull_t sS = 0, sD = 0;
#pragma unroll
            for (int c = 0; c < NCH; c++) {
                ull_t w = g_cnt64[n * NCH + c];
                sS += (w >> 12) & 0x3FFFFFFull;
                sD += (w >> 38);
            }
            float ds = (float)sS * (1.0f / 65536.0f) + 1.0f; // + self-loop in_w
            float dr = (float)sD * (1.0f / 65536.0f) + 1.0f; // + self-loop out_w
            g_dis2[n] = make_float2(rsqrtf(ds + 1e-12f), rsqrtf(dr + 1e-12f));
        }
        return;
    }
    // ---- scan role (decoupled lookback, rocPRIM pattern) ----
    __shared__ int sd[1024];
    __shared__ int s_ex;
    int b = gb;
    int i = b * 1024 + t;
    int v = 0;
    if (i < NE2) {
        int n = i / NCH;
        int c = i - n * NCH;
        v = (int)(g_cnt64[i] & 0xFFFull) + ((c == n / CHW) ? 1 : 0); // + self-loop slot
    }
    sd[t] = v;
    __syncthreads();
    for (int o = 1; o < 1024; o <<= 1) {
        int tv = (t >= o) ? sd[t - o] : 0;
        __syncthreads();
        sd[t] += tv;
        __syncthreads();
    }
    int incl = sd[t];
    int agg = sd[1023];
    if (t == 0) { // publish aggregate (or final prefix for block 0) ASAP
        atomicExch(&g_scanst[b], ((b == 0 ? 2u : 1u) << 20) | (uint_t)agg);
    }
    if (t < 64) { // wave-parallel lookback: 64 predecessors per round
        int ex = 0;
        if (b > 0) {
            int j = b - 1;
            while (true) {
                int idx = j - 63 + t;
                uint_t wv = (idx >= 0) ? atomicAdd(&g_scanst[idx], 0u) : (2u << 20);
                uint_t fl = wv >> 20;
                unsigned long long m2 = __ballot(fl == 2u);
                unsigned long long m0 = __ballot(fl == 0u);
                if (m2 != 0ull) {
                    int p = 63 - __clzll(m2); // highest lane holding an inclusive prefix
                    unsigned long long above = (p == 63) ? 0ull : (~0ull << (p + 1));
                    if ((m0 & above) != 0ull) continue; // unknown between prefix and j: retry
                    int contrib = (t >= p) ? (int)(wv & 0xFFFFFu) : 0;
#pragma unroll
                    for (int o = 1; o < 64; o <<= 1) contrib += __shfl_xor(contrib, o);
                    ex += contrib;
                    break;
                } else {
                    if (m0 != 0ull) continue; // some predecessor not published yet: retry
                    int contrib = (int)(wv & 0xFFFFFu);
#pragma unroll
                    for (int o = 1; o < 64; o <<= 1) contrib += __shfl_xor(contrib, o);
                    ex += contrib;
                    j -= 64;
                }
            }
        }
        if (t == 0) {
            atomicExch(&g_scanst[b], (2u << 20) | (uint_t)(ex + agg));
            s_ex = ex;
        }
    }
    __syncthreads();
    if (i < NE2) g_offs2[i] = incl - v + s_ex;
    if (b == 0 && t == 0) g_offs2[NE2] = CSR_E; // sentinel
}

// ---------------- CSR fill: FINAL folded weights (r14 verbatim) ----------------

__global__ __launch_bounds__(256) void fill_all() {
    if (blockIdx.x == 0 && threadIdx.x < 512) g_scanst[threadIdx.x] = 0;
    for (int i = blockIdx.x * 256 + threadIdx.x; i < NE2; i += gridDim.x * 256)
        g_cnt64[i] = 0; // re-arm for next launch (scan+deg already consumed)
    int e = blockIdx.x * 256 + threadIdx.x;
    if (e < N_EDGES) {
        uint4 stg = g_estage[e];
        int s = (int)stg.x;
        int r = (int)stg.y;
        float c2 = __uint_as_float(stg.z);
        float s2 = 1.0f - c2;
        uint_t rk = stg.w;
        float2 dss = g_dis2[s]; // (dis_s, dis_r) of s
        float2 dsr = g_dis2[r];
        int pf = g_offs2[r * NCH + s / CHW] + (int)(rk & 0xffffu);
        int pr = g_offs2[s * NCH + r / CHW] + (int)(rk >> 16);
        // fwd (dst=r, src=s): wS'=dis_s[s]*c2, wD'=dis_r[s]*s2
        g_csr8[pf] = make_uint2((uint_t)s, packw(dss.x * c2, dss.y * s2));
        // rev (dst=s, src=r): wS'=dis_s[r]*s2, wD'=dis_r[r]*c2
        g_csr8[pr] = make_uint2((uint_t)r, packw(dsr.x * s2, dsr.y * c2));
    }
    if (e < N_NODES) { // self-loop at last slot of its bucket; out=in=1
        int b = e * NCH + e / CHW;
        float2 d = g_dis2[e];
        g_csr8[g_offs2[b + 1] - 1] = make_uint2((uint_t)e, packw(d.x, d.y));
    }
}

// ---------------- FUSED layer: PIPELINED 4-batch broadcast gather -> LDS -> MFMA ----------------
// r14 post-mortem: gather latency-bound at 2.5x the BW floor; the wave-uniform
// break between 4-batches kept in-flight loads alternating 4->0. Now software-
// pipelined: while FMA-ing batch A, batch B's 4 shfls + 4 row loads issue
// (next batch in-window, or next window's batch 0 from the prefetched enext
// registers) -> >=4 loads continuously in flight. +~20 VGPR (vB/eyB) is safe:
// r5's failure was 80 VGPR; ~64-70 still allows 7 waves/SIMD > measured
// residency. FMA order and val-guards unchanged -> bit-identical output.

template <int LAYER>
__global__ __launch_bounds__(256) void fused_layer(const ushort_t* __restrict__ xext,
                                                   void* __restrict__ outp) {
    __shared__ ushort_t tA[16 * 256];                       // agg tile, swizzled
    __shared__ ushort_t tH[(LAYER == 1) ? 16 * 128 : 1];    // h2 tile (L1 only)
    int w = threadIdx.x >> 6;
    int lane = threadIdx.x & 63;
    int gsel = lane >> 4; // which of the wave's 4 nodes
    int r = lane & 15;    // feature sub-block: feats 8r..8r+7
    int lrow = w * 4 + gsel;            // local row 0..15
    int node = blockIdx.x * 16 + lrow;  // exact: 3125*16 = 50000
    const ushort_t* xin = (LAYER == 0) ? (g_is16 ? xext : g_xcvt) : g_h1;

    int ks = g_offs2[node * NCH];
    int ke = g_offs2[node * NCH + NCH];
    int c0 = ke - ks;
    int cmax = c0;
    cmax = max(cmax, __shfl_xor(cmax, 16));
    cmax = max(cmax, __shfl_xor(cmax, 32));

    float accS[8], accD[8];
#pragma unroll
    for (int f = 0; f < 8; f++) { accS[f] = 0.f; accD[f] = 0.f; }

    // lane r holds entry (k + r) of its group's list (clamped; weight zeroed past c0)
    uint2 ecur = g_csr8[ks + min(r, c0 - 1)];
    int lbase = lane & 48; // group base within wave

    // prologue: stage batch 0 (cmax >= 1 guaranteed: self-loop)
    uint_t eyA[4];
    bf16x8 vA[4];
#pragma unroll
    for (int j = 0; j < 4; j++) {
        uint_t ex = (uint_t)__shfl((int)ecur.x, lbase | j, 64);
        eyA[j] = (uint_t)__shfl((int)ecur.y, lbase | j, 64);
        vA[j] = *(const bf16x8*)(xin + (size_t)ex * 128 + r * 8);
    }

    for (int k = 0; k < cmax; k += 16) {
        uint2 enext = ecur;
        if (k + 16 < cmax) enext = g_csr8[ks + min(k + 16 + r, c0 - 1)];
#pragma unroll
        for (int h = 0; h < 4; h++) {
            int kh = k + h * 4;
            if (kh >= cmax) break; // wave-uniform
            // prefetch next batch into B while A is consumed
            uint_t eyB[4];
            bf16x8 vB[4];
            bool more = (kh + 4) < cmax; // wave-uniform
            if (more) {
                uint2 esrc = (h < 3) ? ecur : enext;
                int jb = (h < 3) ? (h + 1) * 4 : 0;
#pragma unroll
                for (int j = 0; j < 4; j++) {
                    uint_t ex = (uint_t)__shfl((int)esrc.x, lbase | (jb + j), 64);
                    eyB[j] = (uint_t)__shfl((int)esrc.y, lbase | (jb + j), 64);
                    vB[j] = *(const bf16x8*)(xin + (size_t)ex * 128 + r * 8);
                }
            }
            // FMA current batch A (order identical to r14 -> bit-identical)
#pragma unroll
            for (int j = 0; j < 4; j++) {
                bool val = (kh + j) < c0;
                float ws_ = val ? unpl(eyA[j]) : 0.f;
                float wd_ = val ? unph(eyA[j]) : 0.f;
#pragma unroll
                for (int f = 0; f < 8; f++) {
                    float xv = bf2f((ushort_t)vA[j][f]);
                    accS[f] = fmaf(ws_, xv, accS[f]);
                    accD[f] = fmaf(wd_, xv, accD[f]);
                }
            }
            if (more) {
#pragma unroll
                for (int j = 0; j < 4; j++) { eyA[j] = eyB[j]; vA[j] = vB[j]; }
            }
        }
        ecur = enext;
    }

    float2 dn = g_dis2[node];
    float fs = 0.5f * dn.y; // S channel: 0.5 * dis_r[dst]
    float fd = 0.5f * dn.x; // D channel: 0.5 * dis_s[dst]
    uint_t oS[4], oD[4];
#pragma unroll
    for (int p = 0; p < 4; p++) {
        oS[p] = ((uint_t)f2bf(accS[2 * p + 1] * fs) << 16) | (uint_t)f2bf(accS[2 * p] * fs);
        oD[p] = ((uint_t)f2bf(accD[2 * p + 1] * fd) << 16) | (uint_t)f2bf(accD[2 * p] * fd);
    }
    int swA = (lrow & 7) << 4;
    *(uint4*)((char*)tA + ((lrow * 512 + r * 16) ^ swA)) = make_uint4(oS[0], oS[1], oS[2], oS[3]);
    *(uint4*)((char*)tA + ((lrow * 512 + 256 + r * 16) ^ swA)) = make_uint4(oD[0], oD[1], oD[2], oD[3]);
    __syncthreads();

    // ---- phase B: GEMM on the 16-row tile; wave w owns cols w*32..w*32+31 ----
    int cc = lane & 15;
    int q = lane >> 4;
    int csw = (cc & 7) << 4;
    const ushort_t* Bp = (LAYER == 0) ? g_bp1 : g_bp2;
    const float* bias = (LAYER == 0) ? g_bc1 : g_bc2;
    f32x4 acc0 = {0.f, 0.f, 0.f, 0.f};
    f32x4 acc1 = {0.f, 0.f, 0.f, 0.f};
#pragma unroll
    for (int kb = 0; kb < 8; kb++) {
        bf16x8 a = *(const bf16x8*)((const char*)tA + ((cc * 512 + kb * 64 + q * 16) ^ csw));
        bf16x8 b0 = *(const bf16x8*)(Bp + (((kb * 128 + w * 32 + cc) << 5) + q * 8));
        bf16x8 b1 = *(const bf16x8*)(Bp + (((kb * 128 + w * 32 + 16 + cc) << 5) + q * 8));
        acc0 = __builtin_amdgcn_mfma_f32_16x16x32_bf16(a, b0, acc0, 0, 0, 0);
        acc1 = __builtin_amdgcn_mfma_f32_16x16x32_bf16(a, b1, acc1, 0, 0, 0);
    }
    int mb = blockIdx.x * 16;
    float bi0 = bias[w * 32 + cc];
    float bi1 = bias[w * 32 + 16 + cc];
    if (LAYER == 0) {
#pragma unroll
        for (int rr = 0; rr < 4; rr++) {
            int m = mb + q * 4 + rr;
            g_h1[(size_t)m * 128 + w * 32 + cc] = f2bf(fmaxf(acc0[rr] + bi0, 0.f));
            g_h1[(size_t)m * 128 + w * 32 + 16 + cc] = f2bf(fmaxf(acc1[rr] + bi1, 0.f));
        }
    } else {
#pragma unroll
        for (int rr = 0; rr < 4; rr++) {
            int ml = q * 4 + rr;
            int msw = (ml & 7) << 4;
            *(ushort_t*)((char*)tH + ((ml * 256 + (w * 32 + cc) * 2) ^ msw)) =
                f2bf(fmaxf(acc0[rr] + bi0, 0.f));
            *(ushort_t*)((char*)tH + ((ml * 256 + (w * 32 + 16 + cc) * 2) ^ msw)) =
                f2bf(fmaxf(acc1[rr] + bi1, 0.f));
        }
        __syncthreads();
        // ---- phase C: readout GEMM, K=128, N=64; wave w owns cols w*16..w*16+15 ----
        f32x4 a3 = {0.f, 0.f, 0.f, 0.f};
#pragma unroll
        for (int kb = 0; kb < 4; kb++) {
            bf16x8 a = *(const bf16x8*)((const char*)tH + ((cc * 256 + kb * 64 + q * 16) ^ csw));
            bf16x8 b = *(const bf16x8*)(g_bp3 + (((kb * 64 + w * 16 + cc) << 5) + q * 8));
            a3 = __builtin_amdgcn_mfma_f32_16x16x32_bf16(a, b, a3, 0, 0, 0);
        }
        int is16 = g_is16;
        float bi = g_bro[w * 16 + cc];
#pragma unroll
        for (int rr = 0; rr < 4; rr++) {
            int m = mb + q * 4 + rr;
            float v = a3[rr] + bi;
            if (is16)
                ((ushort_t*)outp)[(size_t)m * 64 + w * 16 + cc] = f2bf(v);
            else
                ((float*)outp)[(size_t)m * 64 + w * 16 + cc] = v;
        }
    }
}

// ---------------- launch ----------------

static inline int cdiv(int a, int b) { return (a + b - 1) / b; }

extern "C" void kernel_launch(void* const* d_in, const int* in_sizes, int n_in,
                              void* d_out, int out_size, void* d_ws, size_t ws_size,
                              hipStream_t stream) {
    const void* x = d_in[0]; // [50000][128]
    const int* eidx = (const int*)d_in[1];
    const void* theta = d_in[2];
    const void* W1s = d_in[3];
    const void* W1d = d_in[4];
    const void* b1s = d_in[5];
    const void* b1d = d_in[6];
    const void* W2s = d_in[7];
    const void* W2d = d_in[8];
    const void* b2s = d_in[9];
    const void* b2d = d_in[10];
    const void* Wro = d_in[11];
    const void* bro = d_in[12];
    (void)in_sizes; (void)n_in; (void)out_size; (void)d_ws; (void)ws_size;

    edge_prep<<<EB8 + PB + CB, 256, 0, stream>>>(
        (const uint_t*)x, eidx, (const ushort_t*)theta, (const float*)theta,
        (const ushort_t*)W1s, (const float*)W1s, (const ushort_t*)W1d, (const float*)W1d,
        (const ushort_t*)b1s, (const float*)b1s, (const ushort_t*)b1d, (const float*)b1d,
        (const ushort_t*)W2s, (const float*)W2s, (const ushort_t*)W2d, (const float*)W2d,
        (const ushort_t*)b2s, (const float*)b2s, (const ushort_t*)b2d, (const float*)b2d,
        (const ushort_t*)Wro, (const float*)Wro, (const ushort_t*)bro, (const float*)bro);
    scan_deg<<<RB_SCAN + RB_DEGC, 1024, 0, stream>>>();
    fill_all<<<cdiv(N_EDGES, 256), 256, 0, stream>>>();

    const int AB = N_NODES / 16; // 3125 blocks, 16 nodes each (exact)
    fused_layer<0><<<AB, 256, 0, stream>>>((const ushort_t*)x, nullptr);
    fused_layer<1><<<AB, 256, 0, stream>>>(nullptr, d_out);
}

// Round 17
// 246.403 us; speedup vs baseline: 1.0147x; 1.0147x over previous
//
#include <hip/hip_runtime.h>
#include <hip/hip_fp16.h>

#define N_NODES 50000
#define N_EDGES 400000
#define CSR_E (2 * N_EDGES + N_NODES) /* 850000, fits 20 bits */
#define NCH 10        /* source chunks */
#define CHW 5000      /* chunk width: 5000 nodes * 256B = 1.28MB window */
#define NE2 (N_NODES * NCH) /* buckets: (node, chunk), node-major contiguous */
#define EB8 196       /* cdiv(N_EDGES,2048) edge blocks, 8 edges/thread */
#define PB 288        /* prep blocks: (2*32768+8192)/256 */
#define CB 512        /* conv blocks (grid-stride; no-op when bf16 input) */
#define RB_SCAN 489   /* cdiv(NE2,1024) scan blocks */
#define RB_DEGC 49    /* cdiv(N_NODES,1024) deg-extract blocks (ride the scan dispatch) */

typedef unsigned short ushort_t;
typedef unsigned int uint_t;
typedef unsigned long long ull_t;
typedef __attribute__((ext_vector_type(8))) short bf16x8;
typedef __attribute__((ext_vector_type(4))) float f32x4;

__device__ __forceinline__ float bf2f(ushort_t u) {
    return __uint_as_float(((uint_t)u) << 16);
}
__device__ __forceinline__ ushort_t f2bf(float f) {
    uint_t b = __float_as_uint(f);
    b += 0x7FFFu + ((b >> 16) & 1u); // RNE
    return (ushort_t)(b >> 16);
}
// fp16 pair packing for CSR entry weights (low = S-channel, high = D-channel)
__device__ __forceinline__ uint_t packw(float a, float b) {
    return ((uint_t)__half_as_ushort(__float2half(b)) << 16) |
           (uint_t)__half_as_ushort(__float2half(a));
}
__device__ __forceinline__ float unpl(uint_t w) {
    return __half2float(__ushort_as_half((ushort_t)(w & 0xffffu)));
}
__device__ __forceinline__ float unph(uint_t w) {
    return __half2float(__ushort_as_half((ushort_t)(w >> 16)));
}
// 2^16 fixed-point for degree sums packed into the bucket atomic
__device__ __forceinline__ uint_t fixw(float x) {
    return (uint_t)(x * 65536.0f + 0.5f); // <= 65536, fits 26-bit field
}

// ---------------- static device scratch (module BSS; d_ws untouched) ----------------
// Self-maintaining invariants across launches (graph replay): g_cnt64 zeroed by
// fill_all after scan+deg consumed it; g_scanst zeroed by fill_all. BSS starts 0.
// NOTE (r13 post-mortem): intra-kernel spin barriers are triple-confirmed dead
// on MI355X (r3 coop, r10 multi-phase, r13 single-barrier all regressed 2-5x).
// The ~4us dispatch boundary is strictly cheaper than any device-scope spin.
// NOTE (r15 post-mortem): the fused gather's 4-deep batch at VGPR 48/occ 42% is
// the occupancy x MLP optimum - 2/8-deep, staged-serial, and pipelined variants
// all regressed. Do not touch.

__device__ int g_est;  // edge-index word stride: 1 = int32, 2 = int64
__device__ int g_is16; // 1 = float tensors bf16-packed, 0 = fp32
__device__ __align__(8) float2 g_dis2[N_NODES]; // (dis_s, dis_r)
// bucket word: count(12) | S-sum fix16(26)<<12 | D-sum fix16(26)<<38
// S = sum of in_w (deg_s via pairing identity), D = sum of out_w (deg_r)
__device__ ull_t g_cnt64[NE2];
__device__ int g_offs2[NE2 + 1];
__device__ uint_t g_scanst[512];   // lookback scan status: bits[21:20]=flag, [19:0]=value
__device__ __align__(16) uint4 g_estage[N_EDGES]; // {s, r, c2 bits, ranks(lo=fwd,hi=rev)}
__device__ __align__(16) uint2 g_csr8[CSR_E]; // {src, half2 w}: FINAL src-folded weights
__device__ __align__(16) ushort_t g_h1[(size_t)N_NODES * 128];  // bf16
__device__ __align__(16) ushort_t g_xcvt[(size_t)N_NODES * 128]; // bf16 (fp32-input fallback)
__device__ __align__(16) ushort_t g_bp1[8 * 128 * 32]; // B packed [kb][n][kk] bf16
__device__ __align__(16) ushort_t g_bp2[8 * 128 * 32];
__device__ __align__(16) ushort_t g_bp3[4 * 64 * 32];
__device__ float g_bc1[128];
__device__ float g_bc2[128];
__device__ float g_bro[64];

// ---------------- edge pass + weight prep + conv, role-split by block ----------------
// Blocks [0,EB8): edge role, 8 edges/thread, 16 packed 64-bit atomics
//   back-to-back (rank + both degree sums in ONE atomic per bucket side).
// Blocks [EB8,EB8+PB): Bp/bias prep. Blocks [EB8+PB,..+CB): fp32->bf16 conv.

__global__ __launch_bounds__(256) void edge_prep(
    const uint_t* __restrict__ xw,
    const int* __restrict__ eidx, const ushort_t* __restrict__ th16, const float* __restrict__ th32,
    const ushort_t* W1s16, const float* W1s32, const ushort_t* W1d16, const float* W1d32,
    const ushort_t* b1s16, const float* b1s32, const ushort_t* b1d16, const float* b1d32,
    const ushort_t* W2s16, const float* W2s32, const ushort_t* W2d16, const float* W2d32,
    const ushort_t* b2s16, const float* b2s32, const ushort_t* b2d16, const float* b2d32,
    const ushort_t* Wro16, const float* Wro32, const ushort_t* bro16, const float* bro32) {
    __shared__ int s_flags;
    if (threadIdx.x < 64) {
        uint_t w = xw[threadIdx.x];
        int elo = (w >> 7) & 0xFF;
        unsigned long long mb = __ballot(elo >= 100 && elo <= 150);
        unsigned long long me = __ballot(eidx[2 * threadIdx.x + 1] != 0);
        if (threadIdx.x == 0) {
            int is16v = (__popcll(mb) >= 48) ? 1 : 0;
            int estv = me ? 1 : 2;
            s_flags = is16v | (estv << 1);
        }
    }
    __syncthreads();
    int is16 = s_flags & 1;
    int est = s_flags >> 1;
    int gb = blockIdx.x;
    if (gb == 0 && threadIdx.x == 0) { // publish for later kernels
        g_is16 = is16;
        g_est = est;
    }
    if (gb < EB8) {
        int base = gb * 2048 + threadIdx.x;
        int sv[8], rv[8];
        float th[8];
#pragma unroll
        for (int u = 0; u < 8; u++) {
            int e = base + u * 256;
            if (e < N_EDGES) {
                sv[u] = eidx[(size_t)e * est];
                rv[u] = eidx[((size_t)N_EDGES + e) * est];
                th[u] = is16 ? bf2f(th16[e]) : th32[e];
            } else { sv[u] = 0; rv[u] = 0; th[u] = 0.f; }
        }
        float c2v[8];
#pragma unroll
        for (int u = 0; u < 8; u++) {
            float sn, cs_;
            sincosf(th[u], &sn, &cs_);
            c2v[u] = cs_ * cs_;
        }
        uint_t rf[8], rr_[8];
#pragma unroll
        for (int u = 0; u < 8; u++) {
            int e = base + u * 256;
            if (e < N_EDGES) {
                uint_t fc2 = fixw(c2v[u]);
                uint_t fs2 = fixw(1.0f - c2v[u]);
                // fwd entry lands in r's bucket: in_w=s2 (S), out_w=c2 (D)
                ull_t af = 1ull | ((ull_t)fs2 << 12) | ((ull_t)fc2 << 38);
                // rev entry lands in s's bucket: in_w=c2 (S), out_w=s2 (D)
                ull_t ar = 1ull | ((ull_t)fc2 << 12) | ((ull_t)fs2 << 38);
                ull_t retf = atomicAdd(&g_cnt64[rv[u] * NCH + sv[u] / CHW], af);
                ull_t retr = atomicAdd(&g_cnt64[sv[u] * NCH + rv[u] / CHW], ar);
                rf[u] = (uint_t)(retf & 0xFFFull);
                rr_[u] = (uint_t)(retr & 0xFFFull);
            } else { rf[u] = 0; rr_[u] = 0; }
        }
#pragma unroll
        for (int u = 0; u < 8; u++) {
            int e = base + u * 256;
            if (e < N_EDGES)
                g_estage[e] = make_uint4((uint_t)sv[u], (uint_t)rv[u], __float_as_uint(c2v[u]),
                                         rf[u] | (rr_[u] << 16));
        }
        return;
    }
    if (gb < EB8 + PB) {
        int t = (gb - EB8) * 256 + threadIdx.x; // 0..73727
        if (t < 2 * 32768) { // hidden layers
            int layer = t >> 15;
            int i = t & 32767;
            const ushort_t* Ws16 = layer ? W2s16 : W1s16;
            const float* Ws32 = layer ? W2s32 : W1s32;
            const ushort_t* Wd16 = layer ? W2d16 : W1d16;
            const float* Wd32 = layer ? W2d32 : W1d32;
            ushort_t* Bp = layer ? g_bp2 : g_bp1;
            int k = i >> 7, n = i & 127;
            ushort_t v;
            if (k < 128) {
                int idx = k * 128 + n;
                v = is16 ? Ws16[idx] : f2bf(Ws32[idx]);
            } else {
                int idx = (k - 128) * 128 + n;
                v = is16 ? Wd16[idx] : f2bf(Wd32[idx]);
            }
            int kb = k >> 5, kk = k & 31;
            Bp[((kb * 128 + n) << 5) + kk] = v;
            if (i < 128) {
                const ushort_t* bs16 = layer ? b2s16 : b1s16;
                const float* bs32 = layer ? b2s32 : b1s32;
                const ushort_t* bd16 = layer ? b2d16 : b1d16;
                const float* bd32 = layer ? b2d32 : b1d32;
                float a = is16 ? bf2f(bs16[i]) : bs32[i];
                float b = is16 ? bf2f(bd16[i]) : bd32[i];
                (layer ? g_bc2 : g_bc1)[i] = 0.5f * (a + b);
            }
        } else { // readout (t < 73728)
            int i = t - 2 * 32768;
            int k = i >> 6, n = i & 63;
            ushort_t v = is16 ? Wro16[i] : f2bf(Wro32[i]);
            int kb = k >> 5, kk = k & 31;
            g_bp3[((kb * 64 + n) << 5) + kk] = v;
            if (i < 64) g_bro[i] = is16 ? bf2f(bro16[i]) : bro32[i];
        }
        return;
    }
    // conv role: fp32 -> bf16 (no-op when input already bf16)
    if (is16) return;
    const float* x32 = (const float*)xw;
    const int total = N_NODES * 128 / 8;
    for (int i = (gb - EB8 - PB) * 256 + threadIdx.x; i < total; i += CB * 256) {
        const float4* p = (const float4*)(x32 + (size_t)i * 8);
        float4 a = p[0], b = p[1];
        ushort4 o0, o1;
        o0.x = f2bf(a.x); o0.y = f2bf(a.y); o0.z = f2bf(a.z); o0.w = f2bf(a.w);
        o1.x = f2bf(b.x); o1.y = f2bf(b.y); o1.z = f2bf(b.z); o1.w = f2bf(b.w);
        *(ushort4*)(g_xcvt + (size_t)i * 8) = o0;
        *(ushort4*)(g_xcvt + (size_t)i * 8 + 4) = o1;
    }
}

// ---------------- scan + degree extraction in ONE dispatch ----------------
// Blocks [0,RB_SCAN): decoupled-lookback prefix over counts (low 12 bits of
// cnt64) with self-loop +1 folded arithmetically. Blocks [RB_SCAN,..+RB_DEGC):
// dis2[n] from the packed degree sums of n's 10 buckets. Both roles only READ
// g_cnt64 (no hazard); fill_all zeroes it afterward.

__global__ __launch_bounds__(1024) void scan_deg() {
    int gb = blockIdx.x;
    int t = threadIdx.x;
    if (gb >= RB_SCAN) {
        // ---- deg role ----
        int n = (gb - RB_SCAN) * 1024 + t;
        if (n < N_NODES) {
            ull_t sS = 0, sD = 0;
#pragma unroll
            for (int c = 0; c < NCH; c++) {
                ull_t w = g_cnt64[n * NCH + c];
                sS += (w >> 12) & 0x3FFFFFFull;
                sD += (w >> 38);
            }
            float ds = (float)sS * (1.0f / 65536.0f) + 1.0f; // + self-loop in_w
            float dr = (float)sD * (1.0f / 65536.0f) + 1.0f; // + self-loop out_w
            g_dis2[n] = make_float2(rsqrtf(ds + 1e-12f), rsqrtf(dr + 1e-12f));
        }
        return;
    }
    // ---- scan role (decoupled lookback, rocPRIM pattern) ----
    __shared__ int sd[1024];
    __shared__ int s_ex;
    int b = gb;
    int i = b * 1024 + t;
    int v = 0;
    if (i < NE2) {
        int n = i / NCH;
        int c = i - n * NCH;
        v = (int)(g_cnt64[i] & 0xFFFull) + ((c == n / CHW) ? 1 : 0); // + self-loop slot
    }
    sd[t] = v;
    __syncthreads();
    for (int o = 1; o < 1024; o <<= 1) {
        int tv = (t >= o) ? sd[t - o] : 0;
        __syncthreads();
        sd[t] += tv;
        __syncthreads();
    }
    int incl = sd[t];
    int agg = sd[1023];
    if (t == 0) { // publish aggregate (or final prefix for block 0) ASAP
        atomicExch(&g_scanst[b], ((b == 0 ? 2u : 1u) << 20) | (uint_t)agg);
    }
    if (t < 64) { // wave-parallel lookback: 64 predecessors per round
        int ex = 0;
        if (b > 0) {
            int j = b - 1;
            while (true) {
                int idx = j - 63 + t;
                uint_t wv = (idx >= 0) ? atomicAdd(&g_scanst[idx], 0u) : (2u << 20);
                uint_t fl = wv >> 20;
                unsigned long long m2 = __ballot(fl == 2u);
                unsigned long long m0 = __ballot(fl == 0u);
                if (m2 != 0ull) {
                    int p = 63 - __clzll(m2); // highest lane holding an inclusive prefix
                    unsigned long long above = (p == 63) ? 0ull : (~0ull << (p + 1));
                    if ((m0 & above) != 0ull) continue; // unknown between prefix and j: retry
                    int contrib = (t >= p) ? (int)(wv & 0xFFFFFu) : 0;
#pragma unroll
                    for (int o = 1; o < 64; o <<= 1) contrib += __shfl_xor(contrib, o);
                    ex += contrib;
                    break;
                } else {
                    if (m0 != 0ull) continue; // some predecessor not published yet: retry
                    int contrib = (int)(wv & 0xFFFFFu);
#pragma unroll
                    for (int o = 1; o < 64; o <<= 1) contrib += __shfl_xor(contrib, o);
                    ex += contrib;
                    j -= 64;
                }
            }
        }
        if (t == 0) {
            atomicExch(&g_scanst[b], (2u << 20) | (uint_t)(ex + agg));
            s_ex = ex;
        }
    }
    __syncthreads();
    if (i < NE2) g_offs2[i] = incl - v + s_ex;
    if (b == 0 && t == 0) g_offs2[NE2] = CSR_E; // sentinel
}

// ---------------- CSR fill: FINAL folded weights (single fp16 rounding) ----------------
// dis2 is ready (scan_deg) -> fold src factors here; finalize_w eliminated.
// Self-loop at last slot of its bucket. Re-arms g_scanst and g_cnt64.

__global__ __launch_bounds__(256) void fill_all() {
    if (blockIdx.x == 0 && threadIdx.x < 512) g_scanst[threadIdx.x] = 0;
    for (int i = blockIdx.x * 256 + threadIdx.x; i < NE2; i += gridDim.x * 256)
        g_cnt64[i] = 0; // re-arm for next launch (scan+deg already consumed)
    int e = blockIdx.x * 256 + threadIdx.x;
    if (e < N_EDGES) {
        uint4 stg = g_estage[e];
        int s = (int)stg.x;
        int r = (int)stg.y;
        float c2 = __uint_as_float(stg.z);
        float s2 = 1.0f - c2;
        uint_t rk = stg.w;
        float2 dss = g_dis2[s]; // (dis_s, dis_r) of s
        float2 dsr = g_dis2[r];
        int pf = g_offs2[r * NCH + s / CHW] + (int)(rk & 0xffffu);
        int pr = g_offs2[s * NCH + r / CHW] + (int)(rk >> 16);
        // fwd (dst=r, src=s): wS'=dis_s[s]*c2, wD'=dis_r[s]*s2
        g_csr8[pf] = make_uint2((uint_t)s, packw(dss.x * c2, dss.y * s2));
        // rev (dst=s, src=r): wS'=dis_s[r]*s2, wD'=dis_r[r]*c2
        g_csr8[pr] = make_uint2((uint_t)r, packw(dsr.x * s2, dsr.y * c2));
    }
    if (e < N_NODES) { // self-loop at last slot of its bucket; out=in=1
        int b = e * NCH + e / CHW;
        float2 d = g_dis2[e];
        g_csr8[g_offs2[b + 1] - 1] = make_uint2((uint_t)e, packw(d.x, d.y));
    }
}

// ---------------- FUSED layer: 4-batched broadcast gather -> LDS tile -> MFMA GEMM ----------------
// r6/r11/r14 body verbatim (46-47us, VGPR 48, occ 42% - verified optimum):
// 4-deep branch-free batches, early-exit only between batches; dummy entries
// (clamped, zero weight) add exact +0.0 in unchanged order.

template <int LAYER>
__global__ __launch_bounds__(256) void fused_layer(const ushort_t* __restrict__ xext,
                                                   void* __restrict__ outp) {
    __shared__ ushort_t tA[16 * 256];                       // agg tile, swizzled
    __shared__ ushort_t tH[(LAYER == 1) ? 16 * 128 : 1];    // h2 tile (L1 only)
    int w = threadIdx.x >> 6;
    int lane = threadIdx.x & 63;
    int gsel = lane >> 4; // which of the wave's 4 nodes
    int r = lane & 15;    // feature sub-block: feats 8r..8r+7
    int lrow = w * 4 + gsel;            // local row 0..15
    int node = blockIdx.x * 16 + lrow;  // exact: 3125*16 = 50000
    const ushort_t* xin = (LAYER == 0) ? (g_is16 ? xext : g_xcvt) : g_h1;

    int ks = g_offs2[node * NCH];
    int ke = g_offs2[node * NCH + NCH];
    int c0 = ke - ks;
    int cmax = c0;
    cmax = max(cmax, __shfl_xor(cmax, 16));
    cmax = max(cmax, __shfl_xor(cmax, 32));

    float accS[8], accD[8];
#pragma unroll
    for (int f = 0; f < 8; f++) { accS[f] = 0.f; accD[f] = 0.f; }

    // lane r holds entry (k + r) of its group's list (clamped; weight zeroed past c0)
    uint2 ecur = g_csr8[ks + min(r, c0 - 1)];
    int lbase = lane & 48; // group base within wave
    for (int k = 0; k < cmax; k += 16) {
        uint2 enext = ecur;
        if (k + 16 < cmax) enext = g_csr8[ks + min(k + 16 + r, c0 - 1)];
#pragma unroll
        for (int h = 0; h < 4; h++) { // branch-free 4-batches; exit between batches
            int kh = k + h * 4;
            if (kh >= cmax) break; // wave-uniform
            uint_t eys[4];
            bf16x8 vs[4];
#pragma unroll
            for (int j = 0; j < 4; j++) {
                int jj = h * 4 + j;
                uint_t ex = (uint_t)__shfl((int)ecur.x, lbase | jj, 64);
                eys[j] = (uint_t)__shfl((int)ecur.y, lbase | jj, 64);
                vs[j] = *(const bf16x8*)(xin + (size_t)ex * 128 + r * 8);
            }
#pragma unroll
            for (int j = 0; j < 4; j++) {
                bool val = (kh + j) < c0;
                float ws_ = val ? unpl(eys[j]) : 0.f;
                float wd_ = val ? unph(eys[j]) : 0.f;
#pragma unroll
                for (int f = 0; f < 8; f++) {
                    float xv = bf2f((ushort_t)vs[j][f]);
                    accS[f] = fmaf(ws_, xv, accS[f]);
                    accD[f] = fmaf(wd_, xv, accD[f]);
                }
            }
        }
        ecur = enext;
    }

    float2 dn = g_dis2[node];
    float fs = 0.5f * dn.y; // S channel: 0.5 * dis_r[dst]
    float fd = 0.5f * dn.x; // D channel: 0.5 * dis_s[dst]
    uint_t oS[4], oD[4];
#pragma unroll
    for (int p = 0; p < 4; p++) {
        oS[p] = ((uint_t)f2bf(accS[2 * p + 1] * fs) << 16) | (uint_t)f2bf(accS[2 * p] * fs);
        oD[p] = ((uint_t)f2bf(accD[2 * p + 1] * fd) << 16) | (uint_t)f2bf(accD[2 * p] * fd);
    }
    int swA = (lrow & 7) << 4;
    *(uint4*)((char*)tA + ((lrow * 512 + r * 16) ^ swA)) = make_uint4(oS[0], oS[1], oS[2], oS[3]);
    *(uint4*)((char*)tA + ((lrow * 512 + 256 + r * 16) ^ swA)) = make_uint4(oD[0], oD[1], oD[2], oD[3]);
    __syncthreads();

    // ---- phase B: GEMM on the 16-row tile; wave w owns cols w*32..w*32+31 ----
    int cc = lane & 15;
    int q = lane >> 4;
    int csw = (cc & 7) << 4;
    const ushort_t* Bp = (LAYER == 0) ? g_bp1 : g_bp2;
    const float* bias = (LAYER == 0) ? g_bc1 : g_bc2;
    f32x4 acc0 = {0.f, 0.f, 0.f, 0.f};
    f32x4 acc1 = {0.f, 0.f, 0.f, 0.f};
#pragma unroll
    for (int kb = 0; kb < 8; kb++) {
        bf16x8 a = *(const bf16x8*)((const char*)tA + ((cc * 512 + kb * 64 + q * 16) ^ csw));
        bf16x8 b0 = *(const bf16x8*)(Bp + (((kb * 128 + w * 32 + cc) << 5) + q * 8));
        bf16x8 b1 = *(const bf16x8*)(Bp + (((kb * 128 + w * 32 + 16 + cc) << 5) + q * 8));
        acc0 = __builtin_amdgcn_mfma_f32_16x16x32_bf16(a, b0, acc0, 0, 0, 0);
        acc1 = __builtin_amdgcn_mfma_f32_16x16x32_bf16(a, b1, acc1, 0, 0, 0);
    }
    int mb = blockIdx.x * 16;
    float bi0 = bias[w * 32 + cc];
    float bi1 = bias[w * 32 + 16 + cc];
    if (LAYER == 0) {
#pragma unroll
        for (int rr = 0; rr < 4; rr++) {
            int m = mb + q * 4 + rr;
            g_h1[(size_t)m * 128 + w * 32 + cc] = f2bf(fmaxf(acc0[rr] + bi0, 0.f));
            g_h1[(size_t)m * 128 + w * 32 + 16 + cc] = f2bf(fmaxf(acc1[rr] + bi1, 0.f));
        }
    } else {
#pragma unroll
        for (int rr = 0; rr < 4; rr++) {
            int ml = q * 4 + rr;
            int msw = (ml & 7) << 4;
            *(ushort_t*)((char*)tH + ((ml * 256 + (w * 32 + cc) * 2) ^ msw)) =
                f2bf(fmaxf(acc0[rr] + bi0, 0.f));
            *(ushort_t*)((char*)tH + ((ml * 256 + (w * 32 + 16 + cc) * 2) ^ msw)) =
                f2bf(fmaxf(acc1[rr] + bi1, 0.f));
        }
        __syncthreads();
        // ---- phase C: readout GEMM, K=128, N=64; wave w owns cols w*16..w*16+15 ----
        f32x4 a3 = {0.f, 0.f, 0.f, 0.f};
#pragma unroll
        for (int kb = 0; kb < 4; kb++) {
            bf16x8 a = *(const bf16x8*)((const char*)tH + ((cc * 256 + kb * 64 + q * 16) ^ csw));
            bf16x8 b = *(const bf16x8*)(g_bp3 + (((kb * 64 + w * 16 + cc) << 5) + q * 8));
            a3 = __builtin_amdgcn_mfma_f32_16x16x32_bf16(a, b, a3, 0, 0, 0);
        }
        int is16 = g_is16;
        float bi = g_bro[w * 16 + cc];
#pragma unroll
        for (int rr = 0; rr < 4; rr++) {
            int m = mb + q * 4 + rr;
            float v = a3[rr] + bi;
            if (is16)
                ((ushort_t*)outp)[(size_t)m * 64 + w * 16 + cc] = f2bf(v);
            else
                ((float*)outp)[(size_t)m * 64 + w * 16 + cc] = v;
        }
    }
}

// ---------------- launch ----------------

static inline int cdiv(int a, int b) { return (a + b - 1) / b; }

extern "C" void kernel_launch(void* const* d_in, const int* in_sizes, int n_in,
                              void* d_out, int out_size, void* d_ws, size_t ws_size,
                              hipStream_t stream) {
    const void* x = d_in[0]; // [50000][128]
    const int* eidx = (const int*)d_in[1];
    const void* theta = d_in[2];
    const void* W1s = d_in[3];
    const void* W1d = d_in[4];
    const void* b1s = d_in[5];
    const void* b1d = d_in[6];
    const void* W2s = d_in[7];
    const void* W2d = d_in[8];
    const void* b2s = d_in[9];
    const void* b2d = d_in[10];
    const void* Wro = d_in[11];
    const void* bro = d_in[12];
    (void)in_sizes; (void)n_in; (void)out_size; (void)d_ws; (void)ws_size;

    edge_prep<<<EB8 + PB + CB, 256, 0, stream>>>(
        (const uint_t*)x, eidx, (const ushort_t*)theta, (const float*)theta,
        (const ushort_t*)W1s, (const float*)W1s, (const ushort_t*)W1d, (const float*)W1d,
        (const ushort_t*)b1s, (const float*)b1s, (const ushort_t*)b1d, (const float*)b1d,
        (const ushort_t*)W2s, (const float*)W2s, (const ushort_t*)W2d, (const float*)W2d,
        (const ushort_t*)b2s, (const float*)b2s, (const ushort_t*)b2d, (const float*)b2d,
        (const ushort_t*)Wro, (const float*)Wro, (const ushort_t*)bro, (const float*)bro);
    scan_deg<<<RB_SCAN + RB_DEGC, 1024, 0, stream>>>();
    fill_all<<<cdiv(N_EDGES, 256), 256, 0, stream>>>();

    const int AB = N_NODES / 16; // 3125 blocks, 16 nodes each (exact)
    fused_layer<0><<<AB, 256, 0, stream>>>((const ushort_t*)x, nullptr);
    fused_layer<1><<<AB, 256, 0, stream>>>(nullptr, d_out);
}